// Round 14
// baseline (271.406 us; speedup 1.0000x reference)
//
#include <hip/hip_runtime.h>

// ClassicPINN forward, round 14.
// Round-13 post-mortem: P=2 on the scalar-weight structure REGRESSED
// (146->162us): occupancy 58->30% outweighed halved SMEM traffic -> revert
// to P=1. Round-12 (146us) busy-time analysis: measured 117us VALU-busy vs
// ~54us if v_pk_fma_f32 were cleanly formed; ~2x suggests the compiler is
// emitting 2 scalar v_fma per __builtin_elementwise_fma or inserting s->v
// movs for the weight operand.
// Delta vs round 12 (single change): inner FMA forced to inline-asm
//   v_pk_fma_f32 acc, w(SGPR pair), h(VGPR pair), acc
// "s" constraint = VOP3P's one allowed scalar operand; weights stay on the
// SMEM pipe (s_load, uniform compile-time offsets), zero vector-side loads.
// Same arithmetic (2 fp32 FMAs) -> absmax bit-identical 0.0009765625.

#define NPTS 1048576

typedef float f32x2 __attribute__((ext_vector_type(2)));

struct PinnParams {
    const float* W[15];
    const float* B[15];
};

__device__ __forceinline__ float fast_tanh(float x) {
    // tanh(x) = 1 - 2/(exp(2x)+1); exp(2x)=exp2(x*2*log2e). Clamp +-9.5
    // (v_med3_f32) saturates to 1.0f exactly like tanhf. Same as rounds 1-13.
    x = __builtin_amdgcn_fmed3f(x, -9.5f, 9.5f);
    float e = __builtin_amdgcn_exp2f(x * 2.8853900817779268f);
    return 1.0f - 2.0f * __builtin_amdgcn_rcpf(e + 1.0f);
}

// Packed FMA with weight pinned in an SGPR pair (VOP3P scalar operand).
__device__ __forceinline__ void pk_fma_sw(f32x2& acc, f32x2 w, f32x2 h) {
    asm("v_pk_fma_f32 %0, %1, %2, %0" : "+v"(acc) : "s"(w), "v"(h));
}

// Generic layer, k-pair packed, weights from GLOBAL (uniform -> s_load).
// h2: f32x2[IN/2]; o2: f32x2[OUT/2] (halves written with static indices).
// acc.x accumulates bias+even-k, acc.y odd-k terms; horizontal add at end.
template <int IN, int OUT, bool TANH>
__device__ __forceinline__ void layerK(const float* __restrict__ W,
                                       const float* __restrict__ B,
                                       const f32x2* h2, f32x2* o2) {
    static_assert(IN % 2 == 0 && OUT % 2 == 0, "");
#pragma unroll
    for (int j = 0; j < OUT; ++j) {
        f32x2 acc = {B[j], 0.0f};  // B[j]: uniform s_load
#pragma unroll
        for (int k2 = 0; k2 < IN / 2; ++k2) {
            // uniform row-major pair -> s_load_dwordx2 (SGPR pair)
            const f32x2 w = *reinterpret_cast<const f32x2*>(W + j * IN + 2 * k2);
            pk_fma_sw(acc, w, h2[k2]);
        }
        const float s = acc.x + acc.y;
        const float r = TANH ? fast_tanh(s) : s;
        if (j & 1) o2[j >> 1].y = r; else o2[j >> 1].x = r;
    }
}

// First layer: 3 -> 8, scalar (IN=3 not pair-able; 24 weights).
__device__ __forceinline__ void layer0(const float* __restrict__ W,
                                       const float* __restrict__ B,
                                       float h0, float h1, float h2v, f32x2* o2) {
#pragma unroll
    for (int j = 0; j < 8; ++j) {
        float s = fmaf(W[3 * j + 0], h0, B[j]);
        s = fmaf(W[3 * j + 1], h1, s);
        s = fmaf(W[3 * j + 2], h2v, s);
        const float r = fast_tanh(s);
        if (j & 1) o2[j >> 1].y = r; else o2[j >> 1].x = r;
    }
}

// Last layer: 16 -> 3, no tanh.
__device__ __forceinline__ void layer14(const float* __restrict__ W,
                                        const float* __restrict__ B,
                                        const f32x2* h2, float* o) {
#pragma unroll
    for (int j = 0; j < 3; ++j) {
        f32x2 acc = {B[j], 0.0f};
#pragma unroll
        for (int k2 = 0; k2 < 8; ++k2) {
            const f32x2 w = *reinterpret_cast<const f32x2*>(W + j * 16 + 2 * k2);
            pk_fma_sw(acc, w, h2[k2]);
        }
        o[j] = acc.x + acc.y;
    }
}

__global__ __launch_bounds__(256, 6) void pinn_fwd(const float* __restrict__ coords,
                                                   PinnParams prm,
                                                   float* __restrict__ out) {
    const int t = blockIdx.x * 256 + threadIdx.x;

    // activations as f32x2 pairs, ping-pong; static indices only
    f32x2 a2[16], c2[16];
    const float x = coords[3 * t + 0];
    const float y = coords[3 * t + 1];
    const float z = coords[3 * t + 2];

    layer0(prm.W[0], prm.B[0], x, y, z, a2);          // 3 -> 8
    layerK<8, 8, true>(prm.W[1], prm.B[1], a2, c2);
    layerK<8, 8, true>(prm.W[2], prm.B[2], c2, a2);
    layerK<8, 8, true>(prm.W[3], prm.B[3], a2, c2);
    layerK<8, 8, true>(prm.W[4], prm.B[4], c2, a2);
    layerK<8, 8, true>(prm.W[5], prm.B[5], a2, c2);
    layerK<8, 8, true>(prm.W[6], prm.B[6], c2, a2);
    layerK<8, 16, true>(prm.W[7], prm.B[7], a2, c2);  // 8 -> 16
    layerK<16, 16, true>(prm.W[8], prm.B[8], c2, a2);
    layerK<16, 16, true>(prm.W[9], prm.B[9], a2, c2);
    layerK<16, 32, true>(prm.W[10], prm.B[10], c2, a2); // 16 -> 32
    layerK<32, 32, true>(prm.W[11], prm.B[11], a2, c2);
    layerK<32, 32, true>(prm.W[12], prm.B[12], c2, a2);
    layerK<32, 16, true>(prm.W[13], prm.B[13], a2, c2); // 32 -> 16
    float o[3];
    layer14(prm.W[14], prm.B[14], c2, o);             // 16 -> 3, no tanh

    // outputs concatenated (h[:,0], h[:,1], h[:,2]); out[t] coalesced
    out[t] = o[0];
    out[NPTS + t] = o[1];
    out[2 * NPTS + t] = o[2];
}

extern "C" void kernel_launch(void* const* d_in, const int* in_sizes, int n_in,
                              void* d_out, int out_size, void* d_ws, size_t ws_size,
                              hipStream_t stream) {
    const float* coords = (const float*)d_in[0];
    PinnParams prm;
    for (int l = 0; l < 15; ++l) {
        prm.W[l] = (const float*)d_in[1 + 2 * l];
        prm.B[l] = (const float*)d_in[2 + 2 * l];
    }
    pinn_fwd<<<NPTS / 256, 256, 0, stream>>>(coords, prm, (float*)d_out);
}

// Round 15
// 247.207 us; speedup vs baseline: 1.0979x; 1.0979x over previous
//
#include <hip/hip_runtime.h>

// ClassicPINN forward, round 15.
// Round-14 post-mortem: forced inline-asm v_pk_fma REGRESSED (146->195us):
// operand-constraint marshalling + opaque-asm scheduling broke the compiler's
// interleave (busy ~same, stalls up). Reverted to round-12 codegen (146us
// best: k-pair f32x2, s_load weights, no LDS, SGPR=112, VALUBusy 80%).
// This round: cut provable per-neuron overhead (~2K cyc/wave) outside fma:
//  (1) no tanh clamp — 1-2*rcp(exp2(c*x)+1) saturates to +-1.0f naturally
//      (exp2->inf => rcp->0; exp2->0 => -1); inputs finite.
//  (2) paired tanh: j-pairs share packed mul/add/fma (v_pk_*), scalar
//      exp2/rcp only — halves tanh's VALU portion.
//  (3) outputs written as natural pairs (hadd writes pair halves directly,
//      no conditional .x/.y movs).
// Per-element math identical for |x|<9.5; saturation rounds to same 1.0f.

#define NPTS 1048576

typedef float f32x2 __attribute__((ext_vector_type(2)));

struct PinnParams {
    const float* W[15];
    const float* B[15];
};

// Packed tanh on 2 neuron pre-activations: pk mul/add/fma + scalar exp2/rcp.
__device__ __forceinline__ f32x2 tanh2pk(f32x2 x) {
    const f32x2 t = x * 2.8853900817779268f;            // v_pk_mul_f32
    f32x2 e;
    e.x = __builtin_amdgcn_exp2f(t.x);                  // v_exp_f32
    e.y = __builtin_amdgcn_exp2f(t.y);
    const f32x2 d = e + 1.0f;                           // v_pk_add_f32
    f32x2 r;
    r.x = __builtin_amdgcn_rcpf(d.x);                   // v_rcp_f32
    r.y = __builtin_amdgcn_rcpf(d.y);
    return __builtin_elementwise_fma(f32x2{-2.0f, -2.0f}, r,
                                     f32x2{1.0f, 1.0f});  // v_pk_fma_f32
}

__device__ __forceinline__ float fast_tanh1(float x) {  // scalar form (layer0)
    const float e = __builtin_amdgcn_exp2f(x * 2.8853900817779268f);
    return 1.0f - 2.0f * __builtin_amdgcn_rcpf(e + 1.0f);
}

// Generic layer, k-pair packed, weights from GLOBAL (uniform -> s_load).
// Neurons processed in pairs (j0,j1); o2[i] = {r_j0, r_j1} natural pair.
// acc.x accumulates bias+even-k, acc.y odd-k; per-j k-ascending order kept.
template <int IN, int OUT, bool TANH>
__device__ __forceinline__ void layerK(const float* __restrict__ W,
                                       const float* __restrict__ B,
                                       const f32x2* h2, f32x2* o2) {
    static_assert(IN % 2 == 0 && OUT % 2 == 0, "");
#pragma unroll
    for (int i = 0; i < OUT / 2; ++i) {
        const int j0 = 2 * i, j1 = 2 * i + 1;
        f32x2 acc0 = {B[j0], 0.0f};  // biases: uniform s_load
        f32x2 acc1 = {B[j1], 0.0f};
#pragma unroll
        for (int k2 = 0; k2 < IN / 2; ++k2) {
            // uniform row-major pairs -> SGPR pairs; two independent chains
            const f32x2 w0 = *reinterpret_cast<const f32x2*>(W + j0 * IN + 2 * k2);
            const f32x2 w1 = *reinterpret_cast<const f32x2*>(W + j1 * IN + 2 * k2);
            acc0 = __builtin_elementwise_fma(w0, h2[k2], acc0);
            acc1 = __builtin_elementwise_fma(w1, h2[k2], acc1);
        }
        f32x2 sv;
        sv.x = acc0.x + acc0.y;  // hadd writes pair halves directly
        sv.y = acc1.x + acc1.y;
        o2[i] = TANH ? tanh2pk(sv) : sv;
    }
}

// First layer: 3 -> 8, scalar weights (24), packed tanh on result pairs.
__device__ __forceinline__ void layer0(const float* __restrict__ W,
                                       const float* __restrict__ B,
                                       float h0, float h1, float h2v, f32x2* o2) {
#pragma unroll
    for (int i = 0; i < 4; ++i) {
        const int j0 = 2 * i, j1 = 2 * i + 1;
        float s0 = fmaf(W[3 * j0 + 0], h0, B[j0]);
        s0 = fmaf(W[3 * j0 + 1], h1, s0);
        s0 = fmaf(W[3 * j0 + 2], h2v, s0);
        float s1 = fmaf(W[3 * j1 + 0], h0, B[j1]);
        s1 = fmaf(W[3 * j1 + 1], h1, s1);
        s1 = fmaf(W[3 * j1 + 2], h2v, s1);
        o2[i] = tanh2pk(f32x2{s0, s1});
    }
}

// Last layer: 16 -> 3, no tanh.
__device__ __forceinline__ void layer14(const float* __restrict__ W,
                                        const float* __restrict__ B,
                                        const f32x2* h2, float* o) {
#pragma unroll
    for (int j = 0; j < 3; ++j) {
        f32x2 acc = {B[j], 0.0f};
#pragma unroll
        for (int k2 = 0; k2 < 8; ++k2) {
            const f32x2 w = *reinterpret_cast<const f32x2*>(W + j * 16 + 2 * k2);
            acc = __builtin_elementwise_fma(w, h2[k2], acc);
        }
        o[j] = acc.x + acc.y;
    }
}

__global__ __launch_bounds__(256, 6) void pinn_fwd(const float* __restrict__ coords,
                                                   PinnParams prm,
                                                   float* __restrict__ out) {
    const int t = blockIdx.x * 256 + threadIdx.x;

    // activations as f32x2 pairs, ping-pong; static indices only
    f32x2 a2[16], c2[16];
    const float x = coords[3 * t + 0];
    const float y = coords[3 * t + 1];
    const float z = coords[3 * t + 2];

    layer0(prm.W[0], prm.B[0], x, y, z, a2);            // 3 -> 8
    layerK<8, 8, true>(prm.W[1], prm.B[1], a2, c2);
    layerK<8, 8, true>(prm.W[2], prm.B[2], c2, a2);
    layerK<8, 8, true>(prm.W[3], prm.B[3], a2, c2);
    layerK<8, 8, true>(prm.W[4], prm.B[4], c2, a2);
    layerK<8, 8, true>(prm.W[5], prm.B[5], a2, c2);
    layerK<8, 8, true>(prm.W[6], prm.B[6], c2, a2);
    layerK<8, 16, true>(prm.W[7], prm.B[7], a2, c2);    // 8 -> 16
    layerK<16, 16, true>(prm.W[8], prm.B[8], c2, a2);
    layerK<16, 16, true>(prm.W[9], prm.B[9], a2, c2);
    layerK<16, 32, true>(prm.W[10], prm.B[10], c2, a2); // 16 -> 32
    layerK<32, 32, true>(prm.W[11], prm.B[11], a2, c2);
    layerK<32, 32, true>(prm.W[12], prm.B[12], c2, a2);
    layerK<32, 16, true>(prm.W[13], prm.B[13], a2, c2); // 32 -> 16
    float o[3];
    layer14(prm.W[14], prm.B[14], c2, o);               // 16 -> 3, no tanh

    // outputs concatenated (h[:,0], h[:,1], h[:,2]); out[t] coalesced
    out[t] = o[0];
    out[NPTS + t] = o[1];
    out[2 * NPTS + t] = o[2];
}

extern "C" void kernel_launch(void* const* d_in, const int* in_sizes, int n_in,
                              void* d_out, int out_size, void* d_ws, size_t ws_size,
                              hipStream_t stream) {
    const float* coords = (const float*)d_in[0];
    PinnParams prm;
    for (int l = 0; l < 15; ++l) {
        prm.W[l] = (const float*)d_in[1 + 2 * l];
        prm.B[l] = (const float*)d_in[2 + 2 * l];
    }
    pinn_fwd<<<NPTS / 256, 256, 0, stream>>>(coords, prm, (float*)d_out);
}